// Round 13
// baseline (249.269 us; speedup 1.0000x reference)
//
#include <hip/hip_runtime.h>

// QuantAttnBlock on gfx950, round 21:
//  - kT8 stored PRE-SWIZZLED by k_convqkv (chunk = wave^(n&15), the involution
//    k_qpv's LDS layout uses) -> k_qpv stages K via global_load_lds width=16
//    with linear LDS dest (per-lane global addr kb+t*16, wave-uniform LDS
//    base + w*1024). Register prefetch pipeline for K removed.
//  - gn_stats + wsplit + stat/vsum zeroing merged into ONE k_prep kernel;
//    pipeline is 3 dispatches (prep, convqkv, qpv), no hipMemsetAsync.
// Numerics bit-identical (verified absmax 0.0234375).

#define Bb 4
#define Cc 256
#define Nn 4096
#define NGRP 32
#define LOG2E 1.4426950408889634f

typedef unsigned short u16;
typedef unsigned int   u32;
typedef unsigned char  u8;
typedef __attribute__((ext_vector_type(8))) short bf16x8;
typedef __attribute__((ext_vector_type(4))) float f32x4;
typedef __attribute__((ext_vector_type(4))) int   i32x4;

#define MFMA16(a,b,c)    __builtin_amdgcn_mfma_f32_16x16x32_bf16((a),(b),(c),0,0,0)
#define MFMA_I8(a,b,c)   __builtin_amdgcn_mfma_i32_16x16x64_i8((a),(b),(c),0,0,0)
#define EXP2F(x)         __builtin_amdgcn_exp2f(x)

static __device__ __forceinline__ u16 f2bf(float x){
  u32 u = __float_as_uint(x);
  u += 0x7fffu + ((u >> 16) & 1u);
  return (u16)(u >> 16);
}
static __device__ __forceinline__ float bf2f(u16 h){ return __uint_as_float(((u32)h) << 16); }

static __device__ __forceinline__ void gload_lds16(const u8* g, u8* l){
  __builtin_amdgcn_global_load_lds((const __attribute__((address_space(1))) void*)g,
                                   (__attribute__((address_space(3))) void*)l, 16, 0, 0);
}

union U64c { u16 u[4]; uint2 v; };

// ---------------- prep: GN stats + weight split + zero stat/vsum ----------------
__global__ __launch_bounds__(256) void k_prep(const float* __restrict__ x,
                                              float* __restrict__ mu, float* __restrict__ rs,
                                              const float* __restrict__ wq, const float* __restrict__ wk,
                                              const float* __restrict__ wv, const float* __restrict__ wp,
                                              u16* __restrict__ WH, u16* __restrict__ WL,
                                              u32* __restrict__ statz){
  int bid = blockIdx.x;
  if (bid < 128){
    int bg = bid;
    const float4* p = (const float4*)(x + (size_t)bg * (8 * Nn));
    float s = 0.f, q = 0.f;
    for (int i = threadIdx.x; i < 8*Nn/4; i += 256){
      float4 v = p[i];
      s += v.x + v.y + v.z + v.w;
      q += v.x*v.x + v.y*v.y + v.z*v.z + v.w*v.w;
    }
    __shared__ float rsum[256], rsq[256];
    rsum[threadIdx.x] = s; rsq[threadIdx.x] = q;
    __syncthreads();
    for (int off = 128; off > 0; off >>= 1){
      if (threadIdx.x < off){ rsum[threadIdx.x] += rsum[threadIdx.x+off]; rsq[threadIdx.x] += rsq[threadIdx.x+off]; }
      __syncthreads();
    }
    if (threadIdx.x == 0){
      const float inv = 1.0f / (8*Nn);
      float m = rsum[0]*inv;
      float var = rsq[0]*inv - m*m;
      mu[bg] = m; rs[bg] = rsqrtf(var + 1e-6f);
    }
  } else if (bid < 1152){
    int gid = (bid - 128)*256 + threadIdx.x;
    int mat = gid >> 16, idx = gid & 65535;
    const float* src = (mat == 0) ? wq : (mat == 1) ? wk : (mat == 2) ? wv : wp;
    float w = src[idx];
    u16 h = f2bf(w);
    WH[gid] = h;
    WL[gid] = f2bf(w - bf2f(h));
  } else {
    for (int j = threadIdx.x; j < 8 + Bb*Cc; j += 256) statz[j] = 0;
  }
}

// ------------- Fused GN + QKV conv GEMM + stat/vsum -------------
// kT8 written PRE-SWIZZLED: row n, 16B-chunk position (wave ^ (n&15)).
__global__ __launch_bounds__(1024) void k_convqkv(const float* __restrict__ x,
                                                 const float* __restrict__ gsc, const float* __restrict__ gbi,
                                                 const float* __restrict__ mu, const float* __restrict__ rs,
                                                 const u16* __restrict__ WH, const u16* __restrict__ WL,
                                                 const float* __restrict__ bq, const float* __restrict__ bk,
                                                 const float* __restrict__ bv,
                                                 const float* __restrict__ dq, const float* __restrict__ zq,
                                                 const float* __restrict__ dk, const float* __restrict__ zk,
                                                 const float* __restrict__ dv, const float* __restrict__ zv,
                                                 u8* __restrict__ qT8, u8* __restrict__ kT8,
                                                 u8* __restrict__ v8,
                                                 u32* __restrict__ stat, int* __restrict__ vsum){
  int nt = blockIdx.x, b = blockIdx.y;
  __shared__ u16 Lh[64*256], Ll[64*256];
  __shared__ float yt[64*65];
  __shared__ float sa[256], sb[256];
  __shared__ u32 rowacc[2][64];
  int t = threadIdx.x, lane = t & 63, wave = t >> 6;
  int lo16 = lane & 15, quad = lane >> 4;
  int o0 = wave*16;
  int n0 = nt*64;

  if (t < 256){
    int c = t;
    int bg = b*NGRP + (c >> 3);
    float a = rs[bg] * gsc[c];
    sa[c] = a;
    sb[c] = gbi[c] - mu[bg]*a;
  }
  if (t < 128) rowacc[t >> 6][t & 63] = 0;
  __syncthreads();

  // GN + transpose staging: 4 chunks of 64 channels
  {
    int r  = t >> 4, cq = t & 15;
    int nl = t >> 4, c4 = t & 15;
    #pragma unroll
    for (int ct = 0; ct < 4; ++ct){
      int c0 = ct*64;
      float4 xv = *(const float4*)(x + ((size_t)b*Cc + c0 + r)*Nn + n0 + cq*4);
      float a = sa[c0 + r], bb = sb[c0 + r];
      yt[r*65 + cq*4 + 0] = xv.x*a + bb;
      yt[r*65 + cq*4 + 1] = xv.y*a + bb;
      yt[r*65 + cq*4 + 2] = xv.z*a + bb;
      yt[r*65 + cq*4 + 3] = xv.w*a + bb;
      __syncthreads();
      int cg = c0 + c4*4;
      union { u16 us[4]; uint2 v2; } Ph, Pl;
      #pragma unroll
      for (int uu = 0; uu < 4; ++uu){
        float y = yt[(c4*4 + uu)*65 + nl];
        u16 h = f2bf(y);
        Ph.us[uu] = h; Pl.us[uu] = f2bf(y - bf2f(h));
      }
      int ch = cg >> 3;
      int addr = nl*256 + ((ch ^ (nl & 15)) << 3) + (cg & 7);
      *(uint2*)(Lh + addr) = Ph.v2;
      *(uint2*)(Ll + addr) = Pl.v2;
      __syncthreads();
    }
  }

  // ---- single-pass GEMM: all 3 weight sets live, bh/bl read ONCE ----
  f32x4 zf = {0.f,0.f,0.f,0.f};
  f32x4 aQ[4] = {zf, zf, zf, zf};
  f32x4 aK[4] = {zf, zf, zf, zf};
  f32x4 aV[4] = {zf, zf, zf, zf};
  {
    const u16* wbh = WH + (size_t)(o0 + lo16) * 256 + quad*8;
    const u16* wbl = WL + (size_t)(o0 + lo16) * 256 + quad*8;
    #pragma unroll
    for (int k = 0; k < 8; ++k){
      bf16x8 whq = *(const bf16x8*)(wbh + k*32);
      bf16x8 wlq = *(const bf16x8*)(wbl + k*32);
      bf16x8 whk = *(const bf16x8*)(wbh + 65536 + k*32);
      bf16x8 wlk = *(const bf16x8*)(wbl + 65536 + k*32);
      bf16x8 whv = *(const bf16x8*)(wbh + 131072 + k*32);
      bf16x8 wlv = *(const bf16x8*)(wbl + 131072 + k*32);
      #pragma unroll
      for (int ns = 0; ns < 4; ++ns){
        int r = ns*16 + lo16;
        int ph = ((k*4 + quad) ^ (r & 15)) * 8;
        bf16x8 bh = *(const bf16x8*)(Lh + r*256 + ph);
        bf16x8 bl = *(const bf16x8*)(Ll + r*256 + ph);
        aQ[ns] = MFMA16(whq, bh, aQ[ns]);
        aK[ns] = MFMA16(whk, bh, aK[ns]);
        aV[ns] = MFMA16(whv, bh, aV[ns]);
        aQ[ns] = MFMA16(wlq, bh, aQ[ns]);
        aK[ns] = MFMA16(wlk, bh, aK[ns]);
        aV[ns] = MFMA16(wlv, bh, aV[ns]);
        aQ[ns] = MFMA16(whq, bl, aQ[ns]);
        aK[ns] = MFMA16(whk, bl, aK[ns]);
        aV[ns] = MFMA16(whv, bl, aV[ns]);
      }
    }
  }

  // ---- epilogues ----
  // Q (unswizzled layout)
  {
    float bia[4];
    #pragma unroll
    for (int r = 0; r < 4; ++r) bia[r] = bq[o0 + quad*4 + r];
    float z = zq[0]; float invd = 1.0f / dq[0];
    #pragma unroll
    for (int ns = 0; ns < 4; ++ns){
      int n = nt*64 + ns*16 + lo16;
      u32 wpk = 0;
      int nrm = 0;
      #pragma unroll
      for (int r = 0; r < 4; ++r){
        float v = aQ[ns][r] + bia[r];
        float xq = fminf(fmaxf(rintf(v*invd) + z, 0.f), 255.f);
        int qi = (int)rintf(xq - z);
        nrm += qi*qi;
        wpk |= ((u32)(qi & 255)) << (8*r);
      }
      *(u32*)(qT8 + ((size_t)b*Nn + n)*Cc + o0 + quad*4) = wpk;
      nrm += __shfl_xor(nrm, 16, 64);
      nrm += __shfl_xor(nrm, 32, 64);
      if (lane < 16) atomicAdd(&rowacc[0][ns*16 + lo16], (u32)nrm);
    }
  }
  // K (PRE-SWIZZLED layout: chunk position = wave ^ (n&15), n&15 = lo16)
  {
    float bia[4];
    #pragma unroll
    for (int r = 0; r < 4; ++r) bia[r] = bk[o0 + quad*4 + r];
    float z = zk[0]; float invd = 1.0f / dk[0];
    int swofs = ((wave ^ lo16) << 4) + quad*4;
    #pragma unroll
    for (int ns = 0; ns < 4; ++ns){
      int n = nt*64 + ns*16 + lo16;
      u32 wpk = 0;
      int nrm = 0;
      #pragma unroll
      for (int r = 0; r < 4; ++r){
        float v = aK[ns][r] + bia[r];
        float xq = fminf(fmaxf(rintf(v*invd) + z, 0.f), 255.f);
        int qi = (int)rintf(xq - z);
        nrm += qi*qi;
        wpk |= ((u32)(qi & 255)) << (8*r);
      }
      *(u32*)(kT8 + ((size_t)b*Nn + n)*Cc + swofs) = wpk;
      nrm += __shfl_xor(nrm, 16, 64);
      nrm += __shfl_xor(nrm, 32, 64);
      if (lane < 16) atomicAdd(&rowacc[1][ns*16 + lo16], (u32)nrm);
    }
  }
  // V
  {
    float bia[4];
    #pragma unroll
    for (int r = 0; r < 4; ++r) bia[r] = bv[o0 + quad*4 + r];
    float z = zv[0]; float invd = 1.0f / dv[0];
    int vpart[4] = {0, 0, 0, 0};
    #pragma unroll
    for (int ns = 0; ns < 4; ++ns){
      int n = nt*64 + ns*16 + lo16;
      #pragma unroll
      for (int r = 0; r < 4; ++r){
        float v = aV[ns][r] + bia[r];
        float xq = fminf(fmaxf(rintf(v*invd) + z, 0.f), 255.f);
        int qi = (int)rintf(xq - z);
        vpart[r] += qi;
        v8[((size_t)b*Cc + o0 + quad*4 + r)*Nn + n] = (u8)(qi & 255);
      }
    }
    #pragma unroll
    for (int r = 0; r < 4; ++r){
      #pragma unroll
      for (int m = 1; m < 16; m <<= 1)
        vpart[r] += __shfl_xor(vpart[r], m, 64);
    }
    if (lo16 == 0){
      #pragma unroll
      for (int r = 0; r < 4; ++r)
        atomicAdd(&vsum[b*Cc + o0 + quad*4 + r], vpart[r]);
    }
  }

  __syncthreads();
  if (wave < 2){
    u32 v = rowacc[wave][lane];
    #pragma unroll
    for (int m = 1; m < 64; m <<= 1){
      u32 o = (u32)__shfl_xor((int)v, m, 64);
      v = v > o ? v : o;
    }
    if (lane == 0) atomicMax(&stat[wave*4 + b], v);
  }
}

// ------------- fused attention + proj conv + residual: 1024 thr (16 waves).
// K staged via global_load_lds width=16 from PRE-SWIZZLED kT8 (linear LDS
// dest: per-lane global kb+t*16, wave-uniform LDS base + wave*1024).
// BK=128, 2-deep compute pipeline, V direct, Pt double-buffered. -------------
__global__ __launch_bounds__(1024) void k_qpv(const u8* __restrict__ qT8, const u8* __restrict__ kT8,
                                              const u8* __restrict__ v8,
                                              const u32* __restrict__ stat,
                                              const float* __restrict__ pdq, const float* __restrict__ pdk,
                                              const float* __restrict__ pdw, const float* __restrict__ pzw,
                                              const int* __restrict__ vsum,
                                              const float* __restrict__ pdv,
                                              const u16* __restrict__ WH, const u16* __restrict__ WL,
                                              const float* __restrict__ bp,
                                              const float* __restrict__ xres,
                                              float* __restrict__ outF){
  int nt = blockIdx.x, b = blockIdx.y;
  __shared__ alignas(16) u8  Kt[2][2][64*256];  // [iter-parity][tile-in-pair]
  __shared__ alignas(16) u32 Pt[2][2][64*16];   // [iter-parity][tile-in-pair]
  __shared__ float Lbuf[4][4][16];
  int t = threadIdx.x, lane = t & 63, w = t >> 6;
  int lo16 = lane & 15, q = lane >> 4;
  int ms = w & 3, nsq = w >> 2;

  float sc2 = pdq[0]*pdk[0]*0.0625f*LOG2E;
  float M2 = sc2 * sqrtf((float)stat[b] * (float)stat[4+b]);
  float zw = pzw[0];

  i32x4 qf[4];
  {
    const u8* qb = qT8 + ((size_t)b*Nn + nt*64 + nsq*16 + lo16)*256;
    #pragma unroll
    for (int kk = 0; kk < 4; ++kk)
      qf[kk] = *(const i32x4*)(qb + kk*64 + q*16);
  }

  const u8* kb = kT8 + (size_t)b*Nn*256;   // pre-swizzled
  int wofs = w*1024;                        // wave-uniform LDS offset

  int mrow = ms*16 + lo16;
  int kofs[4];
  #pragma unroll
  for (int kk = 0; kk < 4; ++kk) kofs[kk] = mrow*256 + (((kk*4 + q) ^ (mrow & 15)) << 4);

  const u8* vp = v8 + ((size_t)(b*Cc + w*16 + lo16))*Nn + q*16;

  // ---- pass 1: L(n) ----
  float lr = 0.f;
  {
    const u8* kg = kb + t*16;
    gload_lds16(kg,         Kt[0][0] + wofs);
    gload_lds16(kg + 16384, Kt[0][1] + wofs);
    kg += 32768;
    __syncthreads();
    i32x4 spA0, spB0, spA1, spB1;
    #pragma unroll 2
    for (int i = 0; i < 32; ++i){
      int cur = i & 1;
      if (i < 31){
        gload_lds16(kg,         Kt[cur ^ 1][0] + wofs);
        gload_lds16(kg + 16384, Kt[cur ^ 1][1] + wofs);
        kg += 32768;
      }
      i32x4 sA0 = {0,0,0,0}, sB0 = {0,0,0,0}, sA1 = {0,0,0,0}, sB1 = {0,0,0,0};
      sA0 = MFMA_I8(*(const i32x4*)(Kt[cur][0] + kofs[0]), qf[0], sA0);
      sB0 = MFMA_I8(*(const i32x4*)(Kt[cur][0] + kofs[1]), qf[1], sB0);
      sA1 = MFMA_I8(*(const i32x4*)(Kt[cur][1] + kofs[0]), qf[0], sA1);
      sB1 = MFMA_I8(*(const i32x4*)(Kt[cur][1] + kofs[1]), qf[1], sB1);
      sA0 = MFMA_I8(*(const i32x4*)(Kt[cur][0] + kofs[2]), qf[2], sA0);
      sB0 = MFMA_I8(*(const i32x4*)(Kt[cur][0] + kofs[3]), qf[3], sB0);
      sA1 = MFMA_I8(*(const i32x4*)(Kt[cur][1] + kofs[2]), qf[2], sA1);
      sB1 = MFMA_I8(*(const i32x4*)(Kt[cur][1] + kofs[3]), qf[3], sB1);
      if (i > 0){
        #pragma unroll
        for (int r = 0; r < 4; ++r){
          lr += EXP2F(fmaf((float)(spA0[r] + spB0[r]), sc2, -M2));
          lr += EXP2F(fmaf((float)(spA1[r] + spB1[r]), sc2, -M2));
        }
      }
      spA0 = sA0; spB0 = sB0; spA1 = sA1; spB1 = sB1;
      __syncthreads();
    }
    #pragma unroll
    for (int r = 0; r < 4; ++r){
      lr += EXP2F(fmaf((float)(spA0[r] + spB0[r]), sc2, -M2));
      lr += EXP2F(fmaf((float)(spA1[r] + spB1[r]), sc2, -M2));
    }
  }
  lr += __shfl_xor(lr, 16, 64);
  lr += __shfl_xor(lr, 32, 64);
  if (lane < 16) Lbuf[nsq][ms][lo16] = lr;
  __syncthreads();
  float Ls = Lbuf[nsq][0][lo16] + Lbuf[nsq][1][lo16] + Lbuf[nsq][2][lo16] + Lbuf[nsq][3][lo16];
  float crn = __log2f(1.0f / (pdw[0] * Ls)) - M2;

  // ---- pass 2: 2-deep pipeline over supertiles ----
  i32x4 zi = {0,0,0,0};
  i32x4 acc[4] = {zi,zi,zi,zi};
  int nrow = nsq*16 + lo16;
  int pdst = nrow*16 + ((ms ^ (nrow & 3) ^ ((nrow >> 2) & 3)) << 2) + q;
  int pofs[4];
  #pragma unroll
  for (int ns = 0; ns < 4; ++ns){
    int pr = ns*16 + lo16;
    pofs[ns] = pr*16 + ((q ^ (pr & 3) ^ ((pr >> 2) & 3)) << 2);
  }
  {
    const u8* kg = kb + t*16;
    gload_lds16(kg,         Kt[0][0] + wofs);
    gload_lds16(kg + 16384, Kt[0][1] + wofs);
    kg += 32768;
    const u8* vld = vp + 128;
    i32x4 af0 = *(const i32x4*)(vp);
    i32x4 af1 = *(const i32x4*)(vp + 64);
    i32x4 af0p, af1p, af0pp, af1pp;
    i32x4 spA0, spB0, spA1, spB1;
    __syncthreads();
    #pragma unroll 2
    for (int i = 0; i < 32; ++i){
      int cur = i & 1;
      if (i < 31){
        gload_lds16(kg,         Kt[cur ^ 1][0] + wofs);
        gload_lds16(kg + 16384, Kt[cur ^ 1][1] + wofs);
        kg += 32768;
      }
      i32x4 sA0 = {0,0,0,0}, sB0 = {0,0,0,0}, sA1 = {0,0,0,0}, sB1 = {0,0,0,0};
      sA0 = MFMA_I8(*(const i32x4*)(Kt[cur][0] + kofs[0]), qf[0], sA0);
      sB0 = MFMA_I8(*(const i32x4*)(Kt[cur][0] + kofs[1]), qf[1], sB0);
      sA1 = MFMA_I8(*(const i32x4*)(Kt[cur][1] + kofs[0]), qf[0], sA1);
      sB1 = MFMA_I8(*(const i32x4*)(Kt[cur][1] + kofs[1]), qf[1], sB1);
      sA0 = MFMA_I8(*(const i32x4*)(Kt[cur][0] + kofs[2]), qf[2], sA0);
      sB0 = MFMA_I8(*(const i32x4*)(Kt[cur][0] + kofs[3]), qf[3], sB0);
      sA1 = MFMA_I8(*(const i32x4*)(Kt[cur][1] + kofs[2]), qf[2], sA1);
      sB1 = MFMA_I8(*(const i32x4*)(Kt[cur][1] + kofs[3]), qf[3], sB1);
      if (i > 1){
        acc[0] = MFMA_I8(af0pp, *(const i32x4*)(Pt[cur][0] + pofs[0]), acc[0]);
        acc[1] = MFMA_I8(af0pp, *(const i32x4*)(Pt[cur][0] + pofs[1]), acc[1]);
        acc[2] = MFMA_I8(af0pp, *(const i32x4*)(Pt[cur][0] + pofs[2]), acc[2]);
        acc[3] = MFMA_I8(af0pp, *(const i32x4*)(Pt[cur][0] + pofs[3]), acc[3]);
        acc[0] = MFMA_I8(af1pp, *(const i32x4*)(Pt[cur][1] + pofs[0]), acc[0]);
        acc[1] = MFMA_I8(af1pp, *(const i32x4*)(Pt[cur][1] + pofs[1]), acc[1]);
        acc[2] = MFMA_I8(af1pp, *(const i32x4*)(Pt[cur][1] + pofs[2]), acc[2]);
        acc[3] = MFMA_I8(af1pp, *(const i32x4*)(Pt[cur][1] + pofs[3]), acc[3]);
      }
      if (i > 0){
        u32 wp0 = 0, wp1 = 0;
        #pragma unroll
        for (int r = 0; r < 4; ++r){
          float at0 = EXP2F(fmaf((float)(spA0[r] + spB0[r]), sc2, crn));
          float y0 = fminf(fmaxf(rintf(at0) + zw, 0.f), 255.f);
          wp0 = __builtin_amdgcn_cvt_pk_u8_f32(y0, (u32)r, wp0);
          float at1 = EXP2F(fmaf((float)(spA1[r] + spB1[r]), sc2, crn));
          float y1 = fminf(fmaxf(rintf(at1) + zw, 0.f), 255.f);
          wp1 = __builtin_amdgcn_cvt_pk_u8_f32(y1, (u32)r, wp1);
        }
        Pt[cur ^ 1][0][pdst] = wp0 ^ 0x80808080u;
        Pt[cur ^ 1][1][pdst] = wp1 ^ 0x80808080u;
      }
      spA0 = sA0; spB0 = sB0; spA1 = sA1; spB1 = sB1;
      af0pp = af0p; af0p = af0; af1pp = af1p; af1p = af1;
      if (i < 31){
        af0 = *(const i32x4*)(vld);
        af1 = *(const i32x4*)(vld + 64);
        vld += 128;
      }
      __syncthreads();
    }
    acc[0] = MFMA_I8(af0pp, *(const i32x4*)(Pt[0][0] + pofs[0]), acc[0]);
    acc[1] = MFMA_I8(af0pp, *(const i32x4*)(Pt[0][0] + pofs[1]), acc[1]);
    acc[2] = MFMA_I8(af0pp, *(const i32x4*)(Pt[0][0] + pofs[2]), acc[2]);
    acc[3] = MFMA_I8(af0pp, *(const i32x4*)(Pt[0][0] + pofs[3]), acc[3]);
    acc[0] = MFMA_I8(af1pp, *(const i32x4*)(Pt[0][1] + pofs[0]), acc[0]);
    acc[1] = MFMA_I8(af1pp, *(const i32x4*)(Pt[0][1] + pofs[1]), acc[1]);
    acc[2] = MFMA_I8(af1pp, *(const i32x4*)(Pt[0][1] + pofs[2]), acc[2]);
    acc[3] = MFMA_I8(af1pp, *(const i32x4*)(Pt[0][1] + pofs[3]), acc[3]);
    {
      u32 wp0 = 0, wp1 = 0;
      #pragma unroll
      for (int r = 0; r < 4; ++r){
        float at0 = EXP2F(fmaf((float)(spA0[r] + spB0[r]), sc2, crn));
        float y0 = fminf(fmaxf(rintf(at0) + zw, 0.f), 255.f);
        wp0 = __builtin_amdgcn_cvt_pk_u8_f32(y0, (u32)r, wp0);
        float at1 = EXP2F(fmaf((float)(spA1[r] + spB1[r]), sc2, crn));
        float y1 = fminf(fmaxf(rintf(at1) + zw, 0.f), 255.f);
        wp1 = __builtin_amdgcn_cvt_pk_u8_f32(y1, (u32)r, wp1);
      }
      Pt[1][0][pdst] = wp0 ^ 0x80808080u;
      Pt[1][1][pdst] = wp1 ^ 0x80808080u;
    }
    __syncthreads();
    acc[0] = MFMA_I8(af0p, *(const i32x4*)(Pt[1][0] + pofs[0]), acc[0]);
    acc[1] = MFMA_I8(af0p, *(const i32x4*)(Pt[1][0] + pofs[1]), acc[1]);
    acc[2] = MFMA_I8(af0p, *(const i32x4*)(Pt[1][0] + pofs[2]), acc[2]);
    acc[3] = MFMA_I8(af0p, *(const i32x4*)(Pt[1][0] + pofs[3]), acc[3]);
    acc[0] = MFMA_I8(af1p, *(const i32x4*)(Pt[1][1] + pofs[0]), acc[0]);
    acc[1] = MFMA_I8(af1p, *(const i32x4*)(Pt[1][1] + pofs[1]), acc[1]);
    acc[2] = MFMA_I8(af1p, *(const i32x4*)(Pt[1][1] + pofs[2]), acc[2]);
    acc[3] = MFMA_I8(af1p, *(const i32x4*)(Pt[1][1] + pofs[3]), acc[3]);
  }

  // ---- fused proj conv + residual ----
  u16* Ht = (u16*)Kt;   // overlay (Kt reads finished >=2 barriers ago)
  {
    float s = pdv[0] * pdw[0];
    float corr = s * (128.0f - zw);
    int c0 = w*16 + q*4;
    int kc0 = c0 >> 7;
    int ch8 = (c0 >> 3) & 15;
    int c4  = c0 & 7;
    float cv[4];
    #pragma unroll
    for (int r = 0; r < 4; ++r) cv[r] = corr * (float)vsum[b*Cc + c0 + r];
    #pragma unroll
    for (int ns = 0; ns < 4; ++ns){
      int rrow = ns*16 + lo16;
      U64c Uh;
      #pragma unroll
      for (int r = 0; r < 4; ++r)
        Uh.u[r] = f2bf(s*(float)acc[ns][r] + cv[r]);
      *(uint2*)(Ht + rrow*256 + kc0*128 + ((ch8 ^ (rrow & 7)) << 3) + c4) = Uh.v;
    }
  }
  __syncthreads();
  {
    f32x4 zf = {0.f,0.f,0.f,0.f};
    f32x4 acc2[4] = {zf, zf, zf, zf};
    const u16* wbh = WH + (size_t)3*65536 + (size_t)(w*16 + lo16)*256 + q*8;
    const u16* wbl = WL + (size_t)3*65536 + (size_t)(w*16 + lo16)*256 + q*8;
    #pragma unroll
    for (int kc = 0; kc < 2; ++kc){
      bf16x8 ah[4], al[4];
      #pragma unroll
      for (int k4 = 0; k4 < 4; ++k4){
        ah[k4] = *(const bf16x8*)(wbh + kc*128 + k4*32);
        al[k4] = *(const bf16x8*)(wbl + kc*128 + k4*32);
      }
      #pragma unroll
      for (int k4 = 0; k4 < 4; ++k4){
        #pragma unroll
        for (int ns = 0; ns < 4; ++ns){
          int rrow = ns*16 + lo16;
          bf16x8 bh = *(const bf16x8*)(Ht + rrow*256 + kc*128 + (((k4*4 + q) ^ (rrow & 7)) << 3));
          acc2[ns] = MFMA16(ah[k4], bh, acc2[ns]);
          acc2[ns] = MFMA16(al[k4], bh, acc2[ns]);
        }
      }
    }
    float bia[4];
    #pragma unroll
    for (int r = 0; r < 4; ++r) bia[r] = bp[w*16 + q*4 + r];
    #pragma unroll
    for (int ns = 0; ns < 4; ++ns){
      int n = nt*64 + ns*16 + lo16;
      #pragma unroll
      for (int r = 0; r < 4; ++r){
        size_t a = ((size_t)b*Cc + w*16 + q*4 + r)*Nn + n;
        outF[a] = xres[a] + acc2[ns][r] + bia[r];
      }
    }
  }
}

extern "C" void kernel_launch(void* const* d_in, const int* in_sizes, int n_in,
                              void* d_out, int out_size, void* d_ws, size_t ws_size,
                              hipStream_t stream){
  (void)in_sizes; (void)n_in; (void)out_size; (void)ws_size;
  const float* x   = (const float*)d_in[0];
  const float* gsc = (const float*)d_in[1];
  const float* gbi = (const float*)d_in[2];
  const float* wq  = (const float*)d_in[3];
  const float* bq  = (const float*)d_in[4];
  const float* wk  = (const float*)d_in[5];
  const float* bk  = (const float*)d_in[6];
  const float* wv  = (const float*)d_in[7];
  const float* bv  = (const float*)d_in[8];
  const float* wp  = (const float*)d_in[9];
  const float* bp  = (const float*)d_in[10];
  const float* dq  = (const float*)d_in[11];
  const float* zq  = (const float*)d_in[12];
  const float* dk  = (const float*)d_in[13];
  const float* zk  = (const float*)d_in[14];
  const float* dv  = (const float*)d_in[15];
  const float* zv  = (const float*)d_in[16];
  const float* dw  = (const float*)d_in[17];
  const float* zw  = (const float*)d_in[18];
  float* out = (float*)d_out;

  const size_t SZT = (size_t)Bb*Nn*Cc;
  u16* hT_hi = (u16*)d_ws;            // unused (layout stability)
  u16* hT_lo = hT_hi + SZT;           // unused
  u16* h2    = hT_lo + SZT;           // unused
  u8*  qT8   = (u8*)(h2 + SZT);
  u8*  kT8   = qT8 + SZT;
  u8*  v8    = kT8 + SZT;
  u16* WH    = (u16*)(v8 + SZT);
  u16* WL    = WH + 4*65536;
  float* mu  = (float*)(WL + 4*65536);
  float* rs  = mu + 128;
  u32*  stat = (u32*)(rs + 128);
  int*  vsum = (int*)(stat + 8);

  k_prep<<<dim3(1153), 256, 0, stream>>>(x, mu, rs, wq, wk, wv, wp, WH, WL, stat);

  k_convqkv<<<dim3(Nn/64, Bb), 1024, 0, stream>>>(x, gsc, gbi, mu, rs, WH, WL,
                                                  bq, bk, bv, dq, zq, dk, zk, dv, zv,
                                                  qT8, kT8, v8, stat, vsum);

  k_qpv<<<dim3(Nn/64, Bb), 1024, 0, stream>>>(qT8, kT8, v8, stat, dq, dk, dw, zw, vsum, dv,
                                              WH, WL, bp, x, out);
}

// Round 14
// 235.406 us; speedup vs baseline: 1.0589x; 1.0589x over previous
//
#include <hip/hip_runtime.h>

// QuantAttnBlock on gfx950, round 22: revert r21's global_load_lds K-staging
// (it exposed full load latency at every barrier -- the m97 vmcnt(0)-drain
// trap; k_qpv 96->108 us). Back to r20's register-prefetch staging and
// unswizzled kT8. KEEP r21's k_prep merge (gn_stats+wsplit+zeroing in one
// dispatch; 3-dispatch pipeline).
// Numerics bit-identical (verified absmax 0.0234375).

#define Bb 4
#define Cc 256
#define Nn 4096
#define NGRP 32
#define LOG2E 1.4426950408889634f

typedef unsigned short u16;
typedef unsigned int   u32;
typedef unsigned char  u8;
typedef __attribute__((ext_vector_type(8))) short bf16x8;
typedef __attribute__((ext_vector_type(4))) float f32x4;
typedef __attribute__((ext_vector_type(4))) int   i32x4;

#define MFMA16(a,b,c)    __builtin_amdgcn_mfma_f32_16x16x32_bf16((a),(b),(c),0,0,0)
#define MFMA_I8(a,b,c)   __builtin_amdgcn_mfma_i32_16x16x64_i8((a),(b),(c),0,0,0)
#define EXP2F(x)         __builtin_amdgcn_exp2f(x)

static __device__ __forceinline__ u16 f2bf(float x){
  u32 u = __float_as_uint(x);
  u += 0x7fffu + ((u >> 16) & 1u);
  return (u16)(u >> 16);
}
static __device__ __forceinline__ float bf2f(u16 h){ return __uint_as_float(((u32)h) << 16); }

union U64c { u16 u[4]; uint2 v; };

// ---------------- prep: GN stats + weight split + zero stat/vsum ----------------
__global__ __launch_bounds__(256) void k_prep(const float* __restrict__ x,
                                              float* __restrict__ mu, float* __restrict__ rs,
                                              const float* __restrict__ wq, const float* __restrict__ wk,
                                              const float* __restrict__ wv, const float* __restrict__ wp,
                                              u16* __restrict__ WH, u16* __restrict__ WL,
                                              u32* __restrict__ statz){
  int bid = blockIdx.x;
  if (bid < 128){
    int bg = bid;
    const float4* p = (const float4*)(x + (size_t)bg * (8 * Nn));
    float s = 0.f, q = 0.f;
    for (int i = threadIdx.x; i < 8*Nn/4; i += 256){
      float4 v = p[i];
      s += v.x + v.y + v.z + v.w;
      q += v.x*v.x + v.y*v.y + v.z*v.z + v.w*v.w;
    }
    __shared__ float rsum[256], rsq[256];
    rsum[threadIdx.x] = s; rsq[threadIdx.x] = q;
    __syncthreads();
    for (int off = 128; off > 0; off >>= 1){
      if (threadIdx.x < off){ rsum[threadIdx.x] += rsum[threadIdx.x+off]; rsq[threadIdx.x] += rsq[threadIdx.x+off]; }
      __syncthreads();
    }
    if (threadIdx.x == 0){
      const float inv = 1.0f / (8*Nn);
      float m = rsum[0]*inv;
      float var = rsq[0]*inv - m*m;
      mu[bg] = m; rs[bg] = rsqrtf(var + 1e-6f);
    }
  } else if (bid < 1152){
    int gid = (bid - 128)*256 + threadIdx.x;
    int mat = gid >> 16, idx = gid & 65535;
    const float* src = (mat == 0) ? wq : (mat == 1) ? wk : (mat == 2) ? wv : wp;
    float w = src[idx];
    u16 h = f2bf(w);
    WH[gid] = h;
    WL[gid] = f2bf(w - bf2f(h));
  } else {
    for (int j = threadIdx.x; j < 8 + Bb*Cc; j += 256) statz[j] = 0;
  }
}

// ------------- Fused GN + QKV conv GEMM + stat/vsum (r20 version) -------------
__global__ __launch_bounds__(1024) void k_convqkv(const float* __restrict__ x,
                                                 const float* __restrict__ gsc, const float* __restrict__ gbi,
                                                 const float* __restrict__ mu, const float* __restrict__ rs,
                                                 const u16* __restrict__ WH, const u16* __restrict__ WL,
                                                 const float* __restrict__ bq, const float* __restrict__ bk,
                                                 const float* __restrict__ bv,
                                                 const float* __restrict__ dq, const float* __restrict__ zq,
                                                 const float* __restrict__ dk, const float* __restrict__ zk,
                                                 const float* __restrict__ dv, const float* __restrict__ zv,
                                                 u8* __restrict__ qT8, u8* __restrict__ kT8,
                                                 u8* __restrict__ v8,
                                                 u32* __restrict__ stat, int* __restrict__ vsum){
  int nt = blockIdx.x, b = blockIdx.y;
  __shared__ u16 Lh[64*256], Ll[64*256];
  __shared__ float yt[64*65];
  __shared__ float sa[256], sb[256];
  __shared__ u32 rowacc[2][64];
  int t = threadIdx.x, lane = t & 63, wave = t >> 6;
  int lo16 = lane & 15, quad = lane >> 4;
  int o0 = wave*16;
  int n0 = nt*64;

  if (t < 256){
    int c = t;
    int bg = b*NGRP + (c >> 3);
    float a = rs[bg] * gsc[c];
    sa[c] = a;
    sb[c] = gbi[c] - mu[bg]*a;
  }
  if (t < 128) rowacc[t >> 6][t & 63] = 0;
  __syncthreads();

  // GN + transpose staging: 4 chunks of 64 channels
  {
    int r  = t >> 4, cq = t & 15;
    int nl = t >> 4, c4 = t & 15;
    #pragma unroll
    for (int ct = 0; ct < 4; ++ct){
      int c0 = ct*64;
      float4 xv = *(const float4*)(x + ((size_t)b*Cc + c0 + r)*Nn + n0 + cq*4);
      float a = sa[c0 + r], bb = sb[c0 + r];
      yt[r*65 + cq*4 + 0] = xv.x*a + bb;
      yt[r*65 + cq*4 + 1] = xv.y*a + bb;
      yt[r*65 + cq*4 + 2] = xv.z*a + bb;
      yt[r*65 + cq*4 + 3] = xv.w*a + bb;
      __syncthreads();
      int cg = c0 + c4*4;
      union { u16 us[4]; uint2 v2; } Ph, Pl;
      #pragma unroll
      for (int uu = 0; uu < 4; ++uu){
        float y = yt[(c4*4 + uu)*65 + nl];
        u16 h = f2bf(y);
        Ph.us[uu] = h; Pl.us[uu] = f2bf(y - bf2f(h));
      }
      int ch = cg >> 3;
      int addr = nl*256 + ((ch ^ (nl & 15)) << 3) + (cg & 7);
      *(uint2*)(Lh + addr) = Ph.v2;
      *(uint2*)(Ll + addr) = Pl.v2;
      __syncthreads();
    }
  }

  // ---- single-pass GEMM: all 3 weight sets live, bh/bl read ONCE ----
  f32x4 zf = {0.f,0.f,0.f,0.f};
  f32x4 aQ[4] = {zf, zf, zf, zf};
  f32x4 aK[4] = {zf, zf, zf, zf};
  f32x4 aV[4] = {zf, zf, zf, zf};
  {
    const u16* wbh = WH + (size_t)(o0 + lo16) * 256 + quad*8;
    const u16* wbl = WL + (size_t)(o0 + lo16) * 256 + quad*8;
    #pragma unroll
    for (int k = 0; k < 8; ++k){
      bf16x8 whq = *(const bf16x8*)(wbh + k*32);
      bf16x8 wlq = *(const bf16x8*)(wbl + k*32);
      bf16x8 whk = *(const bf16x8*)(wbh + 65536 + k*32);
      bf16x8 wlk = *(const bf16x8*)(wbl + 65536 + k*32);
      bf16x8 whv = *(const bf16x8*)(wbh + 131072 + k*32);
      bf16x8 wlv = *(const bf16x8*)(wbl + 131072 + k*32);
      #pragma unroll
      for (int ns = 0; ns < 4; ++ns){
        int r = ns*16 + lo16;
        int ph = ((k*4 + quad) ^ (r & 15)) * 8;
        bf16x8 bh = *(const bf16x8*)(Lh + r*256 + ph);
        bf16x8 bl = *(const bf16x8*)(Ll + r*256 + ph);
        aQ[ns] = MFMA16(whq, bh, aQ[ns]);
        aK[ns] = MFMA16(whk, bh, aK[ns]);
        aV[ns] = MFMA16(whv, bh, aV[ns]);
        aQ[ns] = MFMA16(wlq, bh, aQ[ns]);
        aK[ns] = MFMA16(wlk, bh, aK[ns]);
        aV[ns] = MFMA16(wlv, bh, aV[ns]);
        aQ[ns] = MFMA16(whq, bl, aQ[ns]);
        aK[ns] = MFMA16(whk, bl, aK[ns]);
        aV[ns] = MFMA16(whv, bl, aV[ns]);
      }
    }
  }

  // ---- epilogues ----
  // Q
  {
    float bia[4];
    #pragma unroll
    for (int r = 0; r < 4; ++r) bia[r] = bq[o0 + quad*4 + r];
    float z = zq[0]; float invd = 1.0f / dq[0];
    #pragma unroll
    for (int ns = 0; ns < 4; ++ns){
      int n = nt*64 + ns*16 + lo16;
      u32 wpk = 0;
      int nrm = 0;
      #pragma unroll
      for (int r = 0; r < 4; ++r){
        float v = aQ[ns][r] + bia[r];
        float xq = fminf(fmaxf(rintf(v*invd) + z, 0.f), 255.f);
        int qi = (int)rintf(xq - z);
        nrm += qi*qi;
        wpk |= ((u32)(qi & 255)) << (8*r);
      }
      *(u32*)(qT8 + ((size_t)b*Nn + n)*Cc + o0 + quad*4) = wpk;
      nrm += __shfl_xor(nrm, 16, 64);
      nrm += __shfl_xor(nrm, 32, 64);
      if (lane < 16) atomicAdd(&rowacc[0][ns*16 + lo16], (u32)nrm);
    }
  }
  // K
  {
    float bia[4];
    #pragma unroll
    for (int r = 0; r < 4; ++r) bia[r] = bk[o0 + quad*4 + r];
    float z = zk[0]; float invd = 1.0f / dk[0];
    #pragma unroll
    for (int ns = 0; ns < 4; ++ns){
      int n = nt*64 + ns*16 + lo16;
      u32 wpk = 0;
      int nrm = 0;
      #pragma unroll
      for (int r = 0; r < 4; ++r){
        float v = aK[ns][r] + bia[r];
        float xq = fminf(fmaxf(rintf(v*invd) + z, 0.f), 255.f);
        int qi = (int)rintf(xq - z);
        nrm += qi*qi;
        wpk |= ((u32)(qi & 255)) << (8*r);
      }
      *(u32*)(kT8 + ((size_t)b*Nn + n)*Cc + o0 + quad*4) = wpk;
      nrm += __shfl_xor(nrm, 16, 64);
      nrm += __shfl_xor(nrm, 32, 64);
      if (lane < 16) atomicAdd(&rowacc[1][ns*16 + lo16], (u32)nrm);
    }
  }
  // V
  {
    float bia[4];
    #pragma unroll
    for (int r = 0; r < 4; ++r) bia[r] = bv[o0 + quad*4 + r];
    float z = zv[0]; float invd = 1.0f / dv[0];
    int vpart[4] = {0, 0, 0, 0};
    #pragma unroll
    for (int ns = 0; ns < 4; ++ns){
      int n = nt*64 + ns*16 + lo16;
      #pragma unroll
      for (int r = 0; r < 4; ++r){
        float v = aV[ns][r] + bia[r];
        float xq = fminf(fmaxf(rintf(v*invd) + z, 0.f), 255.f);
        int qi = (int)rintf(xq - z);
        vpart[r] += qi;
        v8[((size_t)b*Cc + o0 + quad*4 + r)*Nn + n] = (u8)(qi & 255);
      }
    }
    #pragma unroll
    for (int r = 0; r < 4; ++r){
      #pragma unroll
      for (int m = 1; m < 16; m <<= 1)
        vpart[r] += __shfl_xor(vpart[r], m, 64);
    }
    if (lo16 == 0){
      #pragma unroll
      for (int r = 0; r < 4; ++r)
        atomicAdd(&vsum[b*Cc + o0 + quad*4 + r], vpart[r]);
    }
  }

  __syncthreads();
  if (wave < 2){
    u32 v = rowacc[wave][lane];
    #pragma unroll
    for (int m = 1; m < 64; m <<= 1){
      u32 o = (u32)__shfl_xor((int)v, m, 64);
      v = v > o ? v : o;
    }
    if (lane == 0) atomicMax(&stat[wave*4 + b], v);
  }
}

// ------------- fused attention + proj conv + residual (r20 version) ----------
__global__ __launch_bounds__(1024) void k_qpv(const u8* __restrict__ qT8, const u8* __restrict__ kT8,
                                              const u8* __restrict__ v8,
                                              const u32* __restrict__ stat,
                                              const float* __restrict__ pdq, const float* __restrict__ pdk,
                                              const float* __restrict__ pdw, const float* __restrict__ pzw,
                                              const int* __restrict__ vsum,
                                              const float* __restrict__ pdv,
                                              const u16* __restrict__ WH, const u16* __restrict__ WL,
                                              const float* __restrict__ bp,
                                              const float* __restrict__ xres,
                                              float* __restrict__ outF){
  int nt = blockIdx.x, b = blockIdx.y;
  __shared__ alignas(16) u8  Kt[2][2][64*256];  // [iter-parity][tile-in-pair]
  __shared__ alignas(16) u32 Pt[2][2][64*16];   // [iter-parity][tile-in-pair]
  __shared__ float Lbuf[4][4][16];
  int t = threadIdx.x, lane = t & 63, w = t >> 6;
  int lo16 = lane & 15, q = lane >> 4;
  int ms = w & 3, nsq = w >> 2;

  float sc2 = pdq[0]*pdk[0]*0.0625f*LOG2E;
  float M2 = sc2 * sqrtf((float)stat[b] * (float)stat[4+b]);
  float zw = pzw[0];

  i32x4 qf[4];
  {
    const u8* qb = qT8 + ((size_t)b*Nn + nt*64 + nsq*16 + lo16)*256;
    #pragma unroll
    for (int kk = 0; kk < 4; ++kk)
      qf[kk] = *(const i32x4*)(qb + kk*64 + q*16);
  }

  int krow = t >> 4, kch = t & 15;
  int kdst = krow*256 + ((kch ^ (krow & 15)) << 4);
  const u8* kb = kT8 + (size_t)b*Nn*256;

  int mrow = ms*16 + lo16;
  int kofs[4];
  #pragma unroll
  for (int kk = 0; kk < 4; ++kk) kofs[kk] = mrow*256 + (((kk*4 + q) ^ (mrow & 15)) << 4);

  const u8* vp = v8 + ((size_t)(b*Cc + w*16 + lo16))*Nn + q*16;

  // ---- pass 1: L(n) ----
  float lr = 0.f;
  {
    const u8* kld = kb + (size_t)krow*256 + kch*16;
    uint4 kr0 = *(const uint4*)(kld);
    uint4 kr1 = *(const uint4*)(kld + 16384);
    *(uint4*)(Kt[0][0] + kdst) = kr0;
    *(uint4*)(Kt[0][1] + kdst) = kr1;
    kld += 2*16384;
    kr0 = *(const uint4*)(kld);
    kr1 = *(const uint4*)(kld + 16384);
    kld += 2*16384;
    __syncthreads();
    i32x4 spA0, spB0, spA1, spB1;
    #pragma unroll 2
    for (int i = 0; i < 32; ++i){
      int cur = i & 1;
      i32x4 sA0 = {0,0,0,0}, sB0 = {0,0,0,0}, sA1 = {0,0,0,0}, sB1 = {0,0,0,0};
      sA0 = MFMA_I8(*(const i32x4*)(Kt[cur][0] + kofs[0]), qf[0], sA0);
      sB0 = MFMA_I8(*(const i32x4*)(Kt[cur][0] + kofs[1]), qf[1], sB0);
      sA1 = MFMA_I8(*(const i32x4*)(Kt[cur][1] + kofs[0]), qf[0], sA1);
      sB1 = MFMA_I8(*(const i32x4*)(Kt[cur][1] + kofs[1]), qf[1], sB1);
      sA0 = MFMA_I8(*(const i32x4*)(Kt[cur][0] + kofs[2]), qf[2], sA0);
      sB0 = MFMA_I8(*(const i32x4*)(Kt[cur][0] + kofs[3]), qf[3], sB0);
      sA1 = MFMA_I8(*(const i32x4*)(Kt[cur][1] + kofs[2]), qf[2], sA1);
      sB1 = MFMA_I8(*(const i32x4*)(Kt[cur][1] + kofs[3]), qf[3], sB1);
      if (i < 31){
        *(uint4*)(Kt[cur ^ 1][0] + kdst) = kr0;
        *(uint4*)(Kt[cur ^ 1][1] + kdst) = kr1;
        if (i < 30){
          kr0 = *(const uint4*)(kld);
          kr1 = *(const uint4*)(kld + 16384);
          kld += 2*16384;
        }
      }
      if (i > 0){
        #pragma unroll
        for (int r = 0; r < 4; ++r){
          lr += EXP2F(fmaf((float)(spA0[r] + spB0[r]), sc2, -M2));
          lr += EXP2F(fmaf((float)(spA1[r] + spB1[r]), sc2, -M2));
        }
      }
      spA0 = sA0; spB0 = sB0; spA1 = sA1; spB1 = sB1;
      __syncthreads();
    }
    #pragma unroll
    for (int r = 0; r < 4; ++r){
      lr += EXP2F(fmaf((float)(spA0[r] + spB0[r]), sc2, -M2));
      lr += EXP2F(fmaf((float)(spA1[r] + spB1[r]), sc2, -M2));
    }
  }
  lr += __shfl_xor(lr, 16, 64);
  lr += __shfl_xor(lr, 32, 64);
  if (lane < 16) Lbuf[nsq][ms][lo16] = lr;
  __syncthreads();
  float Ls = Lbuf[nsq][0][lo16] + Lbuf[nsq][1][lo16] + Lbuf[nsq][2][lo16] + Lbuf[nsq][3][lo16];
  float crn = __log2f(1.0f / (pdw[0] * Ls)) - M2;

  // ---- pass 2: 2-deep pipeline over supertiles ----
  i32x4 zi = {0,0,0,0};
  i32x4 acc[4] = {zi,zi,zi,zi};
  int nrow = nsq*16 + lo16;
  int pdst = nrow*16 + ((ms ^ (nrow & 3) ^ ((nrow >> 2) & 3)) << 2) + q;
  int pofs[4];
  #pragma unroll
  for (int ns = 0; ns < 4; ++ns){
    int pr = ns*16 + lo16;
    pofs[ns] = pr*16 + ((q ^ (pr & 3) ^ ((pr >> 2) & 3)) << 2);
  }
  {
    const u8* kld = kb + (size_t)krow*256 + kch*16;
    uint4 kr0 = *(const uint4*)(kld);
    uint4 kr1 = *(const uint4*)(kld + 16384);
    *(uint4*)(Kt[0][0] + kdst) = kr0;
    *(uint4*)(Kt[0][1] + kdst) = kr1;
    kld += 2*16384;
    kr0 = *(const uint4*)(kld);
    kr1 = *(const uint4*)(kld + 16384);
    kld += 2*16384;
    const u8* vld = vp + 128;
    i32x4 af0 = *(const i32x4*)(vp);
    i32x4 af1 = *(const i32x4*)(vp + 64);
    i32x4 af0p, af1p, af0pp, af1pp;
    i32x4 spA0, spB0, spA1, spB1;
    __syncthreads();
    #pragma unroll 2
    for (int i = 0; i < 32; ++i){
      int cur = i & 1;
      i32x4 sA0 = {0,0,0,0}, sB0 = {0,0,0,0}, sA1 = {0,0,0,0}, sB1 = {0,0,0,0};
      sA0 = MFMA_I8(*(const i32x4*)(Kt[cur][0] + kofs[0]), qf[0], sA0);
      sB0 = MFMA_I8(*(const i32x4*)(Kt[cur][0] + kofs[1]), qf[1], sB0);
      sA1 = MFMA_I8(*(const i32x4*)(Kt[cur][1] + kofs[0]), qf[0], sA1);
      sB1 = MFMA_I8(*(const i32x4*)(Kt[cur][1] + kofs[1]), qf[1], sB1);
      sA0 = MFMA_I8(*(const i32x4*)(Kt[cur][0] + kofs[2]), qf[2], sA0);
      sB0 = MFMA_I8(*(const i32x4*)(Kt[cur][0] + kofs[3]), qf[3], sB0);
      sA1 = MFMA_I8(*(const i32x4*)(Kt[cur][1] + kofs[2]), qf[2], sA1);
      sB1 = MFMA_I8(*(const i32x4*)(Kt[cur][1] + kofs[3]), qf[3], sB1);
      if (i < 31){
        *(uint4*)(Kt[cur ^ 1][0] + kdst) = kr0;
        *(uint4*)(Kt[cur ^ 1][1] + kdst) = kr1;
        if (i < 30){
          kr0 = *(const uint4*)(kld);
          kr1 = *(const uint4*)(kld + 16384);
          kld += 2*16384;
        }
      }
      if (i > 1){
        acc[0] = MFMA_I8(af0pp, *(const i32x4*)(Pt[cur][0] + pofs[0]), acc[0]);
        acc[1] = MFMA_I8(af0pp, *(const i32x4*)(Pt[cur][0] + pofs[1]), acc[1]);
        acc[2] = MFMA_I8(af0pp, *(const i32x4*)(Pt[cur][0] + pofs[2]), acc[2]);
        acc[3] = MFMA_I8(af0pp, *(const i32x4*)(Pt[cur][0] + pofs[3]), acc[3]);
        acc[0] = MFMA_I8(af1pp, *(const i32x4*)(Pt[cur][1] + pofs[0]), acc[0]);
        acc[1] = MFMA_I8(af1pp, *(const i32x4*)(Pt[cur][1] + pofs[1]), acc[1]);
        acc[2] = MFMA_I8(af1pp, *(const i32x4*)(Pt[cur][1] + pofs[2]), acc[2]);
        acc[3] = MFMA_I8(af1pp, *(const i32x4*)(Pt[cur][1] + pofs[3]), acc[3]);
      }
      if (i > 0){
        u32 wp0 = 0, wp1 = 0;
        #pragma unroll
        for (int r = 0; r < 4; ++r){
          float at0 = EXP2F(fmaf((float)(spA0[r] + spB0[r]), sc2, crn));
          float y0 = fminf(fmaxf(rintf(at0) + zw, 0.f), 255.f);
          wp0 = __builtin_amdgcn_cvt_pk_u8_f32(y0, (u32)r, wp0);
          float at1 = EXP2F(fmaf((float)(spA1[r] + spB1[r]), sc2, crn));
          float y1 = fminf(fmaxf(rintf(at1) + zw, 0.f), 255.f);
          wp1 = __builtin_amdgcn_cvt_pk_u8_f32(y1, (u32)r, wp1);
        }
        Pt[cur ^ 1][0][pdst] = wp0 ^ 0x80808080u;
        Pt[cur ^ 1][1][pdst] = wp1 ^ 0x80808080u;
      }
      spA0 = sA0; spB0 = sB0; spA1 = sA1; spB1 = sB1;
      af0pp = af0p; af0p = af0; af1pp = af1p; af1p = af1;
      if (i < 31){
        af0 = *(const i32x4*)(vld);
        af1 = *(const i32x4*)(vld + 64);
        vld += 128;
      }
      __syncthreads();
    }
    acc[0] = MFMA_I8(af0pp, *(const i32x4*)(Pt[0][0] + pofs[0]), acc[0]);
    acc[1] = MFMA_I8(af0pp, *(const i32x4*)(Pt[0][0] + pofs[1]), acc[1]);
    acc[2] = MFMA_I8(af0pp, *(const i32x4*)(Pt[0][0] + pofs[2]), acc[2]);
    acc[3] = MFMA_I8(af0pp, *(const i32x4*)(Pt[0][0] + pofs[3]), acc[3]);
    acc[0] = MFMA_I8(af1pp, *(const i32x4*)(Pt[0][1] + pofs[0]), acc[0]);
    acc[1] = MFMA_I8(af1pp, *(const i32x4*)(Pt[0][1] + pofs[1]), acc[1]);
    acc[2] = MFMA_I8(af1pp, *(const i32x4*)(Pt[0][1] + pofs[2]), acc[2]);
    acc[3] = MFMA_I8(af1pp, *(const i32x4*)(Pt[0][1] + pofs[3]), acc[3]);
    {
      u32 wp0 = 0, wp1 = 0;
      #pragma unroll
      for (int r = 0; r < 4; ++r){
        float at0 = EXP2F(fmaf((float)(spA0[r] + spB0[r]), sc2, crn));
        float y0 = fminf(fmaxf(rintf(at0) + zw, 0.f), 255.f);
        wp0 = __builtin_amdgcn_cvt_pk_u8_f32(y0, (u32)r, wp0);
        float at1 = EXP2F(fmaf((float)(spA1[r] + spB1[r]), sc2, crn));
        float y1 = fminf(fmaxf(rintf(at1) + zw, 0.f), 255.f);
        wp1 = __builtin_amdgcn_cvt_pk_u8_f32(y1, (u32)r, wp1);
      }
      Pt[1][0][pdst] = wp0 ^ 0x80808080u;
      Pt[1][1][pdst] = wp1 ^ 0x80808080u;
    }
    __syncthreads();
    acc[0] = MFMA_I8(af0p, *(const i32x4*)(Pt[1][0] + pofs[0]), acc[0]);
    acc[1] = MFMA_I8(af0p, *(const i32x4*)(Pt[1][0] + pofs[1]), acc[1]);
    acc[2] = MFMA_I8(af0p, *(const i32x4*)(Pt[1][0] + pofs[2]), acc[2]);
    acc[3] = MFMA_I8(af0p, *(const i32x4*)(Pt[1][0] + pofs[3]), acc[3]);
    acc[0] = MFMA_I8(af1p, *(const i32x4*)(Pt[1][1] + pofs[0]), acc[0]);
    acc[1] = MFMA_I8(af1p, *(const i32x4*)(Pt[1][1] + pofs[1]), acc[1]);
    acc[2] = MFMA_I8(af1p, *(const i32x4*)(Pt[1][1] + pofs[2]), acc[2]);
    acc[3] = MFMA_I8(af1p, *(const i32x4*)(Pt[1][1] + pofs[3]), acc[3]);
  }

  // ---- fused proj conv + residual ----
  u16* Ht = (u16*)Kt;   // overlay (Kt reads finished >=2 barriers ago)
  {
    float s = pdv[0] * pdw[0];
    float corr = s * (128.0f - zw);
    int c0 = w*16 + q*4;
    int kc0 = c0 >> 7;
    int ch8 = (c0 >> 3) & 15;
    int c4  = c0 & 7;
    float cv[4];
    #pragma unroll
    for (int r = 0; r < 4; ++r) cv[r] = corr * (float)vsum[b*Cc + c0 + r];
    #pragma unroll
    for (int ns = 0; ns < 4; ++ns){
      int rrow = ns*16 + lo16;
      U64c Uh;
      #pragma unroll
      for (int r = 0; r < 4; ++r)
        Uh.u[r] = f2bf(s*(float)acc[ns][r] + cv[r]);
      *(uint2*)(Ht + rrow*256 + kc0*128 + ((ch8 ^ (rrow & 7)) << 3) + c4) = Uh.v;
    }
  }
  __syncthreads();
  {
    f32x4 zf = {0.f,0.f,0.f,0.f};
    f32x4 acc2[4] = {zf, zf, zf, zf};
    const u16* wbh = WH + (size_t)3*65536 + (size_t)(w*16 + lo16)*256 + q*8;
    const u16* wbl = WL + (size_t)3*65536 + (size_t)(w*16 + lo16)*256 + q*8;
    #pragma unroll
    for (int kc = 0; kc < 2; ++kc){
      bf16x8 ah[4], al[4];
      #pragma unroll
      for (int k4 = 0; k4 < 4; ++k4){
        ah[k4] = *(const bf16x8*)(wbh + kc*128 + k4*32);
        al[k4] = *(const bf16x8*)(wbl + kc*128 + k4*32);
      }
      #pragma unroll
      for (int k4 = 0; k4 < 4; ++k4){
        #pragma unroll
        for (int ns = 0; ns < 4; ++ns){
          int rrow = ns*16 + lo16;
          bf16x8 bh = *(const bf16x8*)(Ht + rrow*256 + kc*128 + (((k4*4 + q) ^ (rrow & 7)) << 3));
          acc2[ns] = MFMA16(ah[k4], bh, acc2[ns]);
          acc2[ns] = MFMA16(al[k4], bh, acc2[ns]);
        }
      }
    }
    float bia[4];
    #pragma unroll
    for (int r = 0; r < 4; ++r) bia[r] = bp[w*16 + q*4 + r];
    #pragma unroll
    for (int ns = 0; ns < 4; ++ns){
      int n = nt*64 + ns*16 + lo16;
      #pragma unroll
      for (int r = 0; r < 4; ++r){
        size_t a = ((size_t)b*Cc + w*16 + q*4 + r)*Nn + n;
        outF[a] = xres[a] + acc2[ns][r] + bia[r];
      }
    }
  }
}

extern "C" void kernel_launch(void* const* d_in, const int* in_sizes, int n_in,
                              void* d_out, int out_size, void* d_ws, size_t ws_size,
                              hipStream_t stream){
  (void)in_sizes; (void)n_in; (void)out_size; (void)ws_size;
  const float* x   = (const float*)d_in[0];
  const float* gsc = (const float*)d_in[1];
  const float* gbi = (const float*)d_in[2];
  const float* wq  = (const float*)d_in[3];
  const float* bq  = (const float*)d_in[4];
  const float* wk  = (const float*)d_in[5];
  const float* bk  = (const float*)d_in[6];
  const float* wv  = (const float*)d_in[7];
  const float* bv  = (const float*)d_in[8];
  const float* wp  = (const float*)d_in[9];
  const float* bp  = (const float*)d_in[10];
  const float* dq  = (const float*)d_in[11];
  const float* zq  = (const float*)d_in[12];
  const float* dk  = (const float*)d_in[13];
  const float* zk  = (const float*)d_in[14];
  const float* dv  = (const float*)d_in[15];
  const float* zv  = (const float*)d_in[16];
  const float* dw  = (const float*)d_in[17];
  const float* zw  = (const float*)d_in[18];
  float* out = (float*)d_out;

  const size_t SZT = (size_t)Bb*Nn*Cc;
  u16* hT_hi = (u16*)d_ws;            // unused (layout stability)
  u16* hT_lo = hT_hi + SZT;           // unused
  u16* h2    = hT_lo + SZT;           // unused
  u8*  qT8   = (u8*)(h2 + SZT);
  u8*  kT8   = qT8 + SZT;
  u8*  v8    = kT8 + SZT;
  u16* WH    = (u16*)(v8 + SZT);
  u16* WL    = WH + 4*65536;
  float* mu  = (float*)(WL + 4*65536);
  float* rs  = mu + 128;
  u32*  stat = (u32*)(rs + 128);
  int*  vsum = (int*)(stat + 8);

  k_prep<<<dim3(1153), 256, 0, stream>>>(x, mu, rs, wq, wk, wv, wp, WH, WL, stat);

  k_convqkv<<<dim3(Nn/64, Bb), 1024, 0, stream>>>(x, gsc, gbi, mu, rs, WH, WL,
                                                  bq, bk, bv, dq, zq, dk, zk, dv, zv,
                                                  qT8, kT8, v8, stat, vsum);

  k_qpv<<<dim3(Nn/64, Bb), 1024, 0, stream>>>(qT8, kT8, v8, stat, dq, dk, dw, zw, vsum, dv,
                                              WH, WL, bp, x, out);
}